// Round 3
// baseline (4430.172 us; speedup 1.0000x reference)
//
#include <hip/hip_runtime.h>
#include <hip/hip_bf16.h>

#define B_SZ 32
#define TS 128
#define TT 64
#define TD 63
#define E_DIM 256
#define H_DIM 512
#define G4 2048
#define V_TRG 30000
#define NWG_L 32   // workgroups per LSTM layer

typedef __attribute__((ext_vector_type(8))) short s8v;
typedef __attribute__((ext_vector_type(4))) float f32x4;
typedef unsigned short u16;
typedef unsigned int u32;
typedef unsigned long long u64;

static __device__ __forceinline__ float sigf(float x) {
  x = fminf(fmaxf(x, -30.f), 30.f);
  return 1.0f / (1.0f + __expf(-x));
}
static __device__ __forceinline__ float tanh_(float x) {
  x = fminf(fmaxf(x, -15.f), 15.f);
  float e = __expf(2.0f * x);
  return (e - 1.0f) / (e + 1.0f);
}
static __device__ __forceinline__ u16 f2bf(float x) {
  union { float f; unsigned u; } v; v.f = x;
  unsigned r = v.u + 0x7FFF + ((v.u >> 16) & 1);
  return (u16)(r >> 16);
}

// ---------------- weight fp32 -> bf16 conversion ----------------
struct Cvt { const float* s; u16* d; int n; };
struct Cvt9 { Cvt m[9]; };

__global__ void cvt_kernel(Cvt9 c) {
  const Cvt cv = c.m[blockIdx.y];
  int i = blockIdx.x * 256 + threadIdx.x;
  const int stride = gridDim.x * 256;
  for (; i < cv.n; i += stride) cv.d[i] = f2bf(cv.s[i]);
}

// ---------------- embedding gather (fp32 table -> bf16 x) ----------------
__global__ void embed_kernel(const int* __restrict__ tok, const float* __restrict__ emb,
                             u16* __restrict__ x, int rows, int tstride) {
  int i = blockIdx.x * 256 + threadIdx.x;
  if (i >= rows * E_DIM) return;
  int e = i & (E_DIM - 1);
  int r = i >> 8;
  int b = r & 31, t = r >> 5;
  int token = tok[b * tstride + t];
  x[i] = f2bf(emb[token * E_DIM + e]);
}

// ---------------- bf16 MFMA GEMM (FC head): C = A(MxK) @ W(NxK)^T + bias ----
template<int MODE>
__global__ __launch_bounds__(256) void gemm_bf16(
    const u16* __restrict__ A, const u16* __restrict__ Bw,
    const float* __restrict__ bias, float* __restrict__ out,
    int M, int N, int K) {
  __shared__ u16 As[128 * 40];   // row stride 40 u16 = 80B (16B pad)
  __shared__ u16 Bs[128 * 40];
  const int nb = blockIdx.x, mb = blockIdx.y;
  const int tid = threadIdx.x;
  const int w = tid >> 6, lane = tid & 63, quad = lane >> 4, cc = lane & 15;
  const int wm = w & 1, wn = w >> 1;
  f32x4 acc[4][4] = {};

  for (int k0 = 0; k0 < K; k0 += 32) {
    #pragma unroll
    for (int i = tid; i < 512; i += 256) {
      int m = i >> 2, kk = (i & 3) << 3;
      int gm = mb * 128 + m;
      s8v va = {};
      if (gm < M) va = *(const s8v*)(A + (size_t)gm * K + k0 + kk);
      *(s8v*)(&As[m * 40 + kk]) = va;
      int gn = nb * 128 + m;
      s8v vb = {};
      if (gn < N) vb = *(const s8v*)(Bw + (size_t)gn * K + k0 + kk);
      *(s8v*)(&Bs[m * 40 + kk]) = vb;
    }
    __syncthreads();
    s8v af[4], bf[4];
    #pragma unroll
    for (int mt = 0; mt < 4; ++mt)
      af[mt] = *(const s8v*)(&As[(wm * 64 + mt * 16 + cc) * 40 + quad * 8]);
    #pragma unroll
    for (int nt = 0; nt < 4; ++nt)
      bf[nt] = *(const s8v*)(&Bs[(wn * 64 + nt * 16 + cc) * 40 + quad * 8]);
    #pragma unroll
    for (int mt = 0; mt < 4; ++mt)
      #pragma unroll
      for (int nt = 0; nt < 4; ++nt)
        acc[mt][nt] = __builtin_amdgcn_mfma_f32_16x16x32_bf16(af[mt], bf[nt], acc[mt][nt], 0, 0, 0);
    __syncthreads();
  }

  #pragma unroll
  for (int mt = 0; mt < 4; ++mt)
    #pragma unroll
    for (int nt = 0; nt < 4; ++nt) {
      int col = nb * 128 + wn * 64 + nt * 16 + cc;
      if (col >= N) continue;
      float bv = bias[col];
      #pragma unroll
      for (int r = 0; r < 4; ++r) {
        int row = mb * 128 + wm * 64 + mt * 16 + quad * 4 + r;
        if (row >= M) continue;
        float v = acc[mt][nt][r] + bv;
        if (MODE == 0) {
          out[(size_t)row * N + col] = v;
        } else {
          int t = row >> 5, b = row & 31;
          out[(size_t)b * (TT * V_TRG) + (size_t)(t + 1) * V_TRG + col] = v;
        }
      }
    }
}

// ---------------- fused 2-layer pipelined LSTM scan, barrier-free ----------
// Tagged h exchange: u32 word = (bf16 h << 16) | (step+1); relaxed agent-scope
// stores/loads (IC-coherent, cache-bypass, immune to cross-iteration staleness).
// Round-3 restructure:
//  - volley16: issue all 64 tagged u64 loads into regs with NO consumer in
//    between (compiler pipelines, counted vmcnt).
//  - packfix16: one tag-check+v_perm-pack pass; stragglers retried per-32B
//    chunk only (16x less retry traffic, ~RT-scale discovery quantum).
//  - L0 runs x-MFMAs while its h-volley is in flight; L1 polls old h1(s-1)
//    first, issues the h0(s) volley, and runs h-MFMAs over that RT.
union PK { u32 w[4]; s8v v; };

#define ALD(p) __hip_atomic_load((p), __ATOMIC_RELAXED, __HIP_MEMORY_SCOPE_AGENT)

static __device__ __forceinline__ void volley16(const u32* __restrict__ base, u64 q[16][4]) {
  #pragma unroll
  for (int ks = 0; ks < 16; ++ks) {
    const u64* p = (const u64*)(base + ks * 32);
    #pragma unroll
    for (int i = 0; i < 4; ++i) q[ks][i] = ALD(p + i);
  }
}

static __device__ __forceinline__ u32 pk(u64 q) {
  // (hi.dword & 0xFFFF0000) | (lo.dword >> 16): one v_perm_b32
  return __builtin_amdgcn_perm((u32)(q >> 32), (u32)q, 0x07060302);
}

static __device__ __forceinline__ void packfix16(const u32* __restrict__ base, u32 tag,
                                                 u64 q[16][4], PK* a) {
  const u64 tp  = (u64)tag | ((u64)tag << 32);
  const u64 MSK = 0x0000FFFF0000FFFFULL;
  unsigned badm = 0;
  #pragma unroll
  for (int ks = 0; ks < 16; ++ks) {
    u64 bad = 0;
    #pragma unroll
    for (int i = 0; i < 4; ++i) bad |= (q[ks][i] ^ tp) & MSK;
    badm |= (bad != 0 ? 1u : 0u) << ks;
    #pragma unroll
    for (int i = 0; i < 4; ++i) a[ks].w[i] = pk(q[ks][i]);
  }
  while (__builtin_expect(badm != 0, 0)) {
    int ks = __builtin_ctz(badm);
    const u64* p = (const u64*)(base + ks * 32);
    u64 qq[4]; u64 bad;
    do {
      bad = 0;
      #pragma unroll
      for (int i = 0; i < 4; ++i) { qq[i] = ALD(p + i); bad |= (qq[i] ^ tp) & MSK; }
      if (bad) __builtin_amdgcn_s_sleep(1);
    } while (bad != 0);
    #pragma unroll
    for (int i = 0; i < 4; ++i) a[ks].w[i] = pk(qq[i]);
    badm &= badm - 1;
  }
}

__global__ __launch_bounds__(128, 1) void lstm2_scan(
    const u16* __restrict__ X,          // [T*32][E] bf16 layer-0 input
    const u16* __restrict__ Wih0,       // [2048][256] bf16
    const u16* __restrict__ Whh0,       // [2048][512] bf16
    const float* __restrict__ bias0,    // [2048]
    const u16* __restrict__ Wih1,       // [2048][512] bf16
    const u16* __restrict__ Whh1,       // [2048][512] bf16
    const float* __restrict__ bias1,    // [2048]
    const u16* __restrict__ h0i, const float* __restrict__ c0i,
    const u16* __restrict__ h1i, const float* __restrict__ c1i,
    u32* __restrict__ H0x,              // [T][32][512] tagged layer-0 h
    u32* __restrict__ H1x,              // [T][32][512] tagged layer-1 h
    u16* __restrict__ Hplain,           // [T*32][512] bf16 (FC input) or null
    u16* __restrict__ h0f, float* __restrict__ c0f,
    u16* __restrict__ h1f, float* __restrict__ c1f,
    int T) {
  __shared__ u16 BsH[64 * 512];         // Whh slice, k-chunk swizzled
  __shared__ u16 BsX[64 * 512];         // Wih slice (L0 uses first 32KB)
  const bool L1 = (blockIdx.x >= NWG_L);
  const int jn = blockIdx.x & 31;
  const int tid = threadIdx.x;
  const int mt = tid >> 6, lane = tid & 63, quad = lane >> 4, cc = lane & 15;

  {
    const u16* Wh = L1 ? Whh1 : Whh0;
    for (int i = tid; i < 64 * 64; i += 128) {
      int col = i >> 6, kc = i & 63;
      int row = (col >> 4) * 512 + jn * 16 + (col & 15);
      s8v v = *(const s8v*)(Wh + (size_t)row * 512 + kc * 8);
      *(s8v*)(&BsH[col * 512 + ((kc + col) & 63) * 8]) = v;
    }
    if (L1) {
      for (int i = tid; i < 64 * 64; i += 128) {
        int col = i >> 6, kc = i & 63;
        int row = (col >> 4) * 512 + jn * 16 + (col & 15);
        s8v v = *(const s8v*)(Wih1 + (size_t)row * 512 + kc * 8);
        *(s8v*)(&BsX[col * 512 + ((kc + col) & 63) * 8]) = v;
      }
    } else {
      for (int i = tid; i < 64 * 32; i += 128) {
        int col = i >> 5, kc = i & 31;
        int row = (col >> 4) * 512 + jn * 16 + (col & 15);
        s8v v = *(const s8v*)(Wih0 + (size_t)row * 256 + kc * 8);
        *(s8v*)(&BsX[col * 256 + ((kc + col) & 31) * 8]) = v;
      }
    }
  }
  __syncthreads();   // only sync in the kernel: LDS is read-only afterwards

  const int br = mt * 16 + quad * 4;                  // batch row base (4 rows)
  const int j  = jn * 16 + cc;                        // hidden col
  const int arow = (mt * 16 + cc) * H_DIM + quad * 8; // consumer fragment offset

  const float* biasp = L1 ? bias1 : bias0;
  float bv4[4];
  #pragma unroll
  for (int g = 0; g < 4; ++g) bv4[g] = biasp[g * 512 + j];

  f32x4 creg;
  {
    const float* ci = L1 ? c1i : c0i;
    #pragma unroll
    for (int r = 0; r < 4; ++r) creg[r] = ci[(br + r) * H_DIM + j];
  }

  if (!L1) {
    // ---------------- layer 0 ----------------
    for (int s = 0; s < T; ++s) {
      // x fragment loads (plain, streaming) — issued first
      const u16* xrow = X + ((size_t)(s * B_SZ) + mt * 16 + cc) * E_DIM + quad * 8;
      s8v xa[8];
      #pragma unroll
      for (int ks = 0; ks < 8; ++ks) xa[ks] = *(const s8v*)(xrow + ks * 32);

      // h volley in flight while x-MFMAs run
      u64 q[16][4];
      const u32* hb = H0x + (size_t)(s - 1) * (B_SZ * H_DIM) + arow;
      if (s > 0) volley16(hb, q);

      f32x4 acc[4] = {};
      #pragma unroll
      for (int ks = 0; ks < 8; ++ks) {
        int kc = ks * 4 + quad;
        #pragma unroll
        for (int g = 0; g < 4; ++g) {
          int col = g * 16 + cc;
          s8v bx = *(const s8v*)(&BsX[col * 256 + ((kc + col) & 31) * 8]);
          acc[g] = __builtin_amdgcn_mfma_f32_16x16x32_bf16(xa[ks], bx, acc[g], 0, 0, 0);
        }
      }

      PK a[16];
      if (s > 0) {
        packfix16(hb, (u32)s, q, a);
      } else {
        #pragma unroll
        for (int ks = 0; ks < 16; ++ks) a[ks].v = *(const s8v*)(h0i + arow + ks * 32);
      }
      #pragma unroll
      for (int ks = 0; ks < 16; ++ks) {
        int kc = ks * 4 + quad;
        #pragma unroll
        for (int g = 0; g < 4; ++g) {
          int col = g * 16 + cc;
          s8v bh = *(const s8v*)(&BsH[col * 512 + ((kc + col) & 63) * 8]);
          acc[g] = __builtin_amdgcn_mfma_f32_16x16x32_bf16(a[ks].v, bh, acc[g], 0, 0, 0);
        }
      }

      u32* hw = H0x + (size_t)s * (B_SZ * H_DIM);
      const u32 tg = (u32)(s + 1);
      #pragma unroll
      for (int r = 0; r < 4; ++r) {
        float gi = acc[0][r] + bv4[0];
        float gf = acc[1][r] + bv4[1];
        float gg = acc[2][r] + bv4[2];
        float go = acc[3][r] + bv4[3];
        float cn = sigf(gf) * creg[r] + sigf(gi) * tanh_(gg);
        float hn = sigf(go) * tanh_(cn);
        creg[r] = cn;
        u16 hb2 = f2bf(hn);
        __hip_atomic_store(&hw[(br + r) * H_DIM + j], ((u32)hb2 << 16) | tg,
                           __ATOMIC_RELAXED, __HIP_MEMORY_SCOPE_AGENT);
        if (s == T - 1 && h0f) {
          h0f[(br + r) * H_DIM + j] = hb2;
          c0f[(br + r) * H_DIM + j] = cn;
        }
      }
    }
  } else {
    // ---------------- layer 1 (one tick behind) ----------------
    for (int s = 0; s < T; ++s) {
      u64 q[16][4];
      PK a[16];
      // h1(s-1): old data, first-shot hit in steady state
      if (s > 0) {
        const u32* hb1 = H1x + (size_t)(s - 1) * (B_SZ * H_DIM) + arow;
        volley16(hb1, q);
        packfix16(hb1, (u32)s, q, a);
      } else {
        #pragma unroll
        for (int ks = 0; ks < 16; ++ks) a[ks].v = *(const s8v*)(h1i + arow + ks * 32);
      }

      // issue h0(s) volley BEFORE h-MFMAs: discovery overlaps compute
      const u32* hb0 = H0x + (size_t)s * (B_SZ * H_DIM) + arow;
      volley16(hb0, q);

      f32x4 acc[4] = {};
      #pragma unroll
      for (int ks = 0; ks < 16; ++ks) {
        int kc = ks * 4 + quad;
        #pragma unroll
        for (int g = 0; g < 4; ++g) {
          int col = g * 16 + cc;
          s8v bh = *(const s8v*)(&BsH[col * 512 + ((kc + col) & 63) * 8]);
          acc[g] = __builtin_amdgcn_mfma_f32_16x16x32_bf16(a[ks].v, bh, acc[g], 0, 0, 0);
        }
      }

      packfix16(hb0, (u32)(s + 1), q, a);
      #pragma unroll
      for (int ks = 0; ks < 16; ++ks) {
        int kc = ks * 4 + quad;
        #pragma unroll
        for (int g = 0; g < 4; ++g) {
          int col = g * 16 + cc;
          s8v bx = *(const s8v*)(&BsX[col * 512 + ((kc + col) & 63) * 8]);
          acc[g] = __builtin_amdgcn_mfma_f32_16x16x32_bf16(a[ks].v, bx, acc[g], 0, 0, 0);
        }
      }

      u32* hw = H1x + (size_t)s * (B_SZ * H_DIM);
      const u32 tg = (u32)(s + 1);
      #pragma unroll
      for (int r = 0; r < 4; ++r) {
        float gi = acc[0][r] + bv4[0];
        float gf = acc[1][r] + bv4[1];
        float gg = acc[2][r] + bv4[2];
        float go = acc[3][r] + bv4[3];
        float cn = sigf(gf) * creg[r] + sigf(gi) * tanh_(gg);
        float hn = sigf(go) * tanh_(cn);
        creg[r] = cn;
        u16 hb2 = f2bf(hn);
        __hip_atomic_store(&hw[(br + r) * H_DIM + j], ((u32)hb2 << 16) | tg,
                           __ATOMIC_RELAXED, __HIP_MEMORY_SCOPE_AGENT);
        if (Hplain)
          Hplain[(size_t)(s * B_SZ + br + r) * H_DIM + j] = hb2;
        if (s == T - 1 && h1f) {
          h1f[(br + r) * H_DIM + j] = hb2;
          c1f[(br + r) * H_DIM + j] = cn;
        }
      }
    }
  }
}

// ---------------- zero out[:, 0, :] ----------------
__global__ void zero_t0_kernel(float* __restrict__ out) {
  int i = blockIdx.x * 256 + threadIdx.x;
  if (i >= B_SZ * V_TRG) return;
  int b = i / V_TRG, v = i - b * V_TRG;
  out[(size_t)b * (TT * V_TRG) + v] = 0.f;
}

extern "C" void kernel_launch(void* const* d_in, const int* in_sizes, int n_in,
                              void* d_out, int out_size, void* d_ws, size_t ws_size,
                              hipStream_t stream) {
  const int*   src     = (const int*)d_in[0];
  const int*   trg     = (const int*)d_in[1];
  const float* enc_emb = (const float*)d_in[2];
  const float* dec_emb = (const float*)d_in[3];
  const float* eW0i = (const float*)d_in[4];
  const float* eW0h = (const float*)d_in[5];
  const float* eb0  = (const float*)d_in[6];
  const float* eW1i = (const float*)d_in[7];
  const float* eW1h = (const float*)d_in[8];
  const float* eb1  = (const float*)d_in[9];
  const float* dW0i = (const float*)d_in[10];
  const float* dW0h = (const float*)d_in[11];
  const float* db0  = (const float*)d_in[12];
  const float* dW1i = (const float*)d_in[13];
  const float* dW1h = (const float*)d_in[14];
  const float* db1  = (const float*)d_in[15];
  const float* fcW  = (const float*)d_in[16];
  const float* fcb  = (const float*)d_in[17];
  float* out = (float*)d_out;

  char* ws = (char*)d_ws;
  size_t off = 0;
  auto alloc = [&](size_t bytes) {
    char* p = ws + off;
    off = (off + bytes + 255) & ~(size_t)255;
    return p;
  };
  u16*   hzero  = (u16*)alloc(B_SZ * H_DIM * 2);
  float* czero  = (float*)alloc(B_SZ * H_DIM * 4);
  u16* eW0i_b = (u16*)alloc((size_t)G4 * E_DIM * 2);
  u16* eW0h_b = (u16*)alloc((size_t)G4 * H_DIM * 2);
  u16* eW1i_b = (u16*)alloc((size_t)G4 * H_DIM * 2);
  u16* eW1h_b = (u16*)alloc((size_t)G4 * H_DIM * 2);
  u16* dW0i_b = (u16*)alloc((size_t)G4 * E_DIM * 2);
  u16* dW0h_b = (u16*)alloc((size_t)G4 * H_DIM * 2);
  u16* dW1i_b = (u16*)alloc((size_t)G4 * H_DIM * 2);
  u16* dW1h_b = (u16*)alloc((size_t)G4 * H_DIM * 2);
  u16* fcW_b  = (u16*)alloc((size_t)V_TRG * H_DIM * 2);
  u16* x_enc  = (u16*)alloc((size_t)TS * B_SZ * E_DIM * 2);
  u16* x_dec  = (u16*)alloc((size_t)TD * B_SZ * E_DIM * 2);
  const size_t PLANE_E = (size_t)TS * B_SZ * H_DIM;
  const size_t PLANE_D = (size_t)TD * B_SZ * H_DIM;
  u32* tagbase = (u32*)alloc((2 * PLANE_E + 2 * PLANE_D) * 4);
  u32* H0e = tagbase;
  u32* H1e = H0e + PLANE_E;
  u32* H0d = H1e + PLANE_E;
  u32* H1d = H0d + PLANE_D;
  u16* H1d_p  = (u16*)alloc((size_t)TD * B_SZ * H_DIM * 2);  // plain bf16 FC input
  u16* hF0    = (u16*)alloc(B_SZ * H_DIM * 2);
  float* cF0  = (float*)alloc(B_SZ * H_DIM * 4);
  u16* hF1    = (u16*)alloc(B_SZ * H_DIM * 2);
  float* cF1  = (float*)alloc(B_SZ * H_DIM * 4);

  hipMemsetAsync(hzero, 0, B_SZ * H_DIM * 2, stream);
  hipMemsetAsync(czero, 0, B_SZ * H_DIM * 4, stream);
  hipMemsetAsync(tagbase, 0, (2 * PLANE_E + 2 * PLANE_D) * 4, stream);

  Cvt9 c9 = {{ {eW0i, eW0i_b, G4 * E_DIM}, {eW0h, eW0h_b, G4 * H_DIM},
               {eW1i, eW1i_b, G4 * H_DIM}, {eW1h, eW1h_b, G4 * H_DIM},
               {dW0i, dW0i_b, G4 * E_DIM}, {dW0h, dW0h_b, G4 * H_DIM},
               {dW1i, dW1i_b, G4 * H_DIM}, {dW1h, dW1h_b, G4 * H_DIM},
               {fcW,  fcW_b,  V_TRG * H_DIM} }};
  cvt_kernel<<<dim3(1024, 9), 256, 0, stream>>>(c9);

  embed_kernel<<<(TS * B_SZ * E_DIM + 255) / 256, 256, 0, stream>>>(src, enc_emb, x_enc, TS * B_SZ, TS);
  embed_kernel<<<(TD * B_SZ * E_DIM + 255) / 256, 256, 0, stream>>>(trg, dec_emb, x_dec, TD * B_SZ, TT);

  // encoder: fused 2-layer pipelined scan (x-gates computed in-kernel)
  lstm2_scan<<<2 * NWG_L, 128, 0, stream>>>(
      x_enc, eW0i_b, eW0h_b, eb0, eW1i_b, eW1h_b, eb1,
      hzero, czero, hzero, czero,
      H0e, H1e, (u16*)nullptr,
      hF0, cF0, hF1, cF1, TS);

  // decoder: init = encoder final states; layer-1 h also stored plain for FC
  lstm2_scan<<<2 * NWG_L, 128, 0, stream>>>(
      x_dec, dW0i_b, dW0h_b, db0, dW1i_b, dW1h_b, db1,
      hF0, cF0, hF1, cF1,
      H0d, H1d, H1d_p,
      (u16*)nullptr, (float*)nullptr, (u16*)nullptr, (float*)nullptr, TD);

  // FC head: logits -> out[b][t+1][v]
  gemm_bf16<1><<<dim3((V_TRG + 127) / 128, (TD * B_SZ + 127) / 128), 256, 0, stream>>>(
      H1d_p, fcW_b, fcb, out, TD * B_SZ, V_TRG, H_DIM);
  zero_t0_kernel<<<(B_SZ * V_TRG + 255) / 256, 256, 0, stream>>>(out);
}

// Round 4
// 2021.391 us; speedup vs baseline: 2.1916x; 2.1916x over previous
//
#include <hip/hip_runtime.h>
#include <hip/hip_bf16.h>

#define B_SZ 32
#define TS 128
#define TT 64
#define TD 63
#define E_DIM 256
#define H_DIM 512
#define G4 2048
#define V_TRG 30000
#define NWG_L 32   // workgroups per LSTM layer

typedef __attribute__((ext_vector_type(8))) short s8v;
typedef __attribute__((ext_vector_type(4))) float f32x4;
typedef unsigned short u16;
typedef unsigned int u32;
typedef unsigned long long u64;

static __device__ __forceinline__ float sigf(float x) {
  x = fminf(fmaxf(x, -30.f), 30.f);
  return 1.0f / (1.0f + __expf(-x));
}
static __device__ __forceinline__ float tanh_(float x) {
  x = fminf(fmaxf(x, -15.f), 15.f);
  float e = __expf(2.0f * x);
  return (e - 1.0f) / (e + 1.0f);
}
static __device__ __forceinline__ u16 f2bf(float x) {
  union { float f; unsigned u; } v; v.f = x;
  unsigned r = v.u + 0x7FFF + ((v.u >> 16) & 1);
  return (u16)(r >> 16);
}

// ---------------- weight fp32 -> bf16 conversion ----------------
struct Cvt { const float* s; u16* d; int n; };
struct Cvt9 { Cvt m[9]; };

__global__ void cvt_kernel(Cvt9 c) {
  const Cvt cv = c.m[blockIdx.y];
  int i = blockIdx.x * 256 + threadIdx.x;
  const int stride = gridDim.x * 256;
  for (; i < cv.n; i += stride) cv.d[i] = f2bf(cv.s[i]);
}

// ---------------- embedding gather (fp32 table -> bf16 x) ----------------
__global__ void embed_kernel(const int* __restrict__ tok, const float* __restrict__ emb,
                             u16* __restrict__ x, int rows, int tstride) {
  int i = blockIdx.x * 256 + threadIdx.x;
  if (i >= rows * E_DIM) return;
  int e = i & (E_DIM - 1);
  int r = i >> 8;
  int b = r & 31, t = r >> 5;
  int token = tok[b * tstride + t];
  x[i] = f2bf(emb[token * E_DIM + e]);
}

// ---------------- bf16 MFMA GEMM (FC head): C = A(MxK) @ W(NxK)^T + bias ----
template<int MODE>
__global__ __launch_bounds__(256) void gemm_bf16(
    const u16* __restrict__ A, const u16* __restrict__ Bw,
    const float* __restrict__ bias, float* __restrict__ out,
    int M, int N, int K) {
  __shared__ u16 As[128 * 40];   // row stride 40 u16 = 80B (16B pad)
  __shared__ u16 Bs[128 * 40];
  const int nb = blockIdx.x, mb = blockIdx.y;
  const int tid = threadIdx.x;
  const int w = tid >> 6, lane = tid & 63, quad = lane >> 4, cc = lane & 15;
  const int wm = w & 1, wn = w >> 1;
  f32x4 acc[4][4] = {};

  for (int k0 = 0; k0 < K; k0 += 32) {
    #pragma unroll
    for (int i = tid; i < 512; i += 256) {
      int m = i >> 2, kk = (i & 3) << 3;
      int gm = mb * 128 + m;
      s8v va = {};
      if (gm < M) va = *(const s8v*)(A + (size_t)gm * K + k0 + kk);
      *(s8v*)(&As[m * 40 + kk]) = va;
      int gn = nb * 128 + m;
      s8v vb = {};
      if (gn < N) vb = *(const s8v*)(Bw + (size_t)gn * K + k0 + kk);
      *(s8v*)(&Bs[m * 40 + kk]) = vb;
    }
    __syncthreads();
    s8v af[4], bf[4];
    #pragma unroll
    for (int mt = 0; mt < 4; ++mt)
      af[mt] = *(const s8v*)(&As[(wm * 64 + mt * 16 + cc) * 40 + quad * 8]);
    #pragma unroll
    for (int nt = 0; nt < 4; ++nt)
      bf[nt] = *(const s8v*)(&Bs[(wn * 64 + nt * 16 + cc) * 40 + quad * 8]);
    #pragma unroll
    for (int mt = 0; mt < 4; ++mt)
      #pragma unroll
      for (int nt = 0; nt < 4; ++nt)
        acc[mt][nt] = __builtin_amdgcn_mfma_f32_16x16x32_bf16(af[mt], bf[nt], acc[mt][nt], 0, 0, 0);
    __syncthreads();
  }

  #pragma unroll
  for (int mt = 0; mt < 4; ++mt)
    #pragma unroll
    for (int nt = 0; nt < 4; ++nt) {
      int col = nb * 128 + wn * 64 + nt * 16 + cc;
      if (col >= N) continue;
      float bv = bias[col];
      #pragma unroll
      for (int r = 0; r < 4; ++r) {
        int row = mb * 128 + wm * 64 + mt * 16 + quad * 4 + r;
        if (row >= M) continue;
        float v = acc[mt][nt][r] + bv;
        if (MODE == 0) {
          out[(size_t)row * N + col] = v;
        } else {
          int t = row >> 5, b = row & 31;
          out[(size_t)b * (TT * V_TRG) + (size_t)(t + 1) * V_TRG + col] = v;
        }
      }
    }
}

// ---------------- fused 2-layer pipelined LSTM scan, barrier-free ----------
// Tagged h exchange: u32 word = (bf16 h << 16) | (step+1).
// Round-4 fixes over round-3:
//  - volley = PLAIN CACHED loads (first toucher per XCD pulls line IC->L2,
//    co-XCD consumers hit L2; ~4-8x less IC pressure).  Stale cached lines
//    just fail the tag check -> chunk retried via L2-BYPASS atomic loads.
//    Per-step-unique addresses mean a stale line is never re-trusted.
//  - fixup is BATCHED-PARALLEL: each round re-issues loads for ALL still-bad
//    chunks (groups of 4 to cap VGPRs), re-checks, sleeps once.  Round-3's
//    serial per-chunk spin (8 stale chunks = 8 serial RTs) is gone.
//  - producer stores stay bypass (dirty-L2 exchange would be non-coherent).
union PK { u32 w[4]; s8v v; };

#define ALD(p) __hip_atomic_load((p), __ATOMIC_RELAXED, __HIP_MEMORY_SCOPE_AGENT)

static __device__ __forceinline__ u32 pk(u64 q) {
  // (hi.dword & 0xFFFF0000) | (lo.dword >> 16): one v_perm_b32
  return __builtin_amdgcn_perm((u32)(q >> 32), (u32)q, 0x07060302);
}

static __device__ __forceinline__ void volley16(const u32* __restrict__ base, u64 q[16][4]) {
  #pragma unroll
  for (int ks = 0; ks < 16; ++ks) {
    const u64* p = (const u64*)(base + ks * 32);
    #pragma unroll
    for (int i = 0; i < 4; ++i) q[ks][i] = p[i];   // plain cached loads
  }
}

static __device__ __forceinline__ unsigned packchk16(u32 tag, const u64 q[16][4], PK* a) {
  const u64 tp  = (u64)tag | ((u64)tag << 32);
  const u64 MSK = 0x0000FFFF0000FFFFULL;
  unsigned badm = 0;
  #pragma unroll
  for (int ks = 0; ks < 16; ++ks) {
    u64 bad = 0;
    #pragma unroll
    for (int i = 0; i < 4; ++i) bad |= (q[ks][i] ^ tp) & MSK;
    badm |= (bad != 0 ? 1u : 0u) << ks;
    #pragma unroll
    for (int i = 0; i < 4; ++i) a[ks].w[i] = pk(q[ks][i]);
  }
  return badm;
}

static __device__ __forceinline__ void fixup16(const u32* __restrict__ base, u32 tag,
                                               unsigned badm, PK* a) {
  const u64 tp  = (u64)tag | ((u64)tag << 32);
  const u64 MSK = 0x0000FFFF0000FFFFULL;
  while (__builtin_expect(badm != 0, 0)) {
    unsigned nb = 0;
    #pragma unroll
    for (int g4 = 0; g4 < 4; ++g4) {
      unsigned gm = (badm >> (g4 * 4)) & 0xF;
      if (!gm) continue;
      u64 q[4][4];
      #pragma unroll
      for (int k = 0; k < 4; ++k) {
        if (gm & (1u << k)) {
          const u64* p = (const u64*)(base + (g4 * 4 + k) * 32);
          #pragma unroll
          for (int i = 0; i < 4; ++i) q[k][i] = ALD(p + i);   // bypass retries
        }
      }
      #pragma unroll
      for (int k = 0; k < 4; ++k) {
        if (gm & (1u << k)) {
          u64 bad = 0;
          #pragma unroll
          for (int i = 0; i < 4; ++i) bad |= (q[k][i] ^ tp) & MSK;
          if (bad) {
            nb |= 1u << (g4 * 4 + k);
          } else {
            #pragma unroll
            for (int i = 0; i < 4; ++i) a[g4 * 4 + k].w[i] = pk(q[k][i]);
          }
        }
      }
    }
    badm = nb;
    if (badm) __builtin_amdgcn_s_sleep(1);
  }
}

__global__ __launch_bounds__(128, 1) void lstm2_scan(
    const u16* __restrict__ X,          // [T*32][E] bf16 layer-0 input
    const u16* __restrict__ Wih0,       // [2048][256] bf16
    const u16* __restrict__ Whh0,       // [2048][512] bf16
    const float* __restrict__ bias0,    // [2048]
    const u16* __restrict__ Wih1,       // [2048][512] bf16
    const u16* __restrict__ Whh1,       // [2048][512] bf16
    const float* __restrict__ bias1,    // [2048]
    const u16* __restrict__ h0i, const float* __restrict__ c0i,
    const u16* __restrict__ h1i, const float* __restrict__ c1i,
    u32* __restrict__ H0x,              // [T][32][512] tagged layer-0 h
    u32* __restrict__ H1x,              // [T][32][512] tagged layer-1 h
    u16* __restrict__ Hplain,           // [T*32][512] bf16 (FC input) or null
    u16* __restrict__ h0f, float* __restrict__ c0f,
    u16* __restrict__ h1f, float* __restrict__ c1f,
    int T) {
  __shared__ u16 BsH[64 * 512];         // Whh slice, k-chunk swizzled
  __shared__ u16 BsX[64 * 512];         // Wih slice (L0 uses first 32KB)
  const bool L1 = (blockIdx.x >= NWG_L);
  const int jn = blockIdx.x & 31;
  const int tid = threadIdx.x;
  const int mt = tid >> 6, lane = tid & 63, quad = lane >> 4, cc = lane & 15;

  {
    const u16* Wh = L1 ? Whh1 : Whh0;
    for (int i = tid; i < 64 * 64; i += 128) {
      int col = i >> 6, kc = i & 63;
      int row = (col >> 4) * 512 + jn * 16 + (col & 15);
      s8v v = *(const s8v*)(Wh + (size_t)row * 512 + kc * 8);
      *(s8v*)(&BsH[col * 512 + ((kc + col) & 63) * 8]) = v;
    }
    if (L1) {
      for (int i = tid; i < 64 * 64; i += 128) {
        int col = i >> 6, kc = i & 63;
        int row = (col >> 4) * 512 + jn * 16 + (col & 15);
        s8v v = *(const s8v*)(Wih1 + (size_t)row * 512 + kc * 8);
        *(s8v*)(&BsX[col * 512 + ((kc + col) & 63) * 8]) = v;
      }
    } else {
      for (int i = tid; i < 64 * 32; i += 128) {
        int col = i >> 5, kc = i & 31;
        int row = (col >> 4) * 512 + jn * 16 + (col & 15);
        s8v v = *(const s8v*)(Wih0 + (size_t)row * 256 + kc * 8);
        *(s8v*)(&BsX[col * 256 + ((kc + col) & 31) * 8]) = v;
      }
    }
  }
  __syncthreads();   // only sync in the kernel: LDS is read-only afterwards

  const int br = mt * 16 + quad * 4;                  // batch row base (4 rows)
  const int j  = jn * 16 + cc;                        // hidden col
  const int arow = (mt * 16 + cc) * H_DIM + quad * 8; // consumer fragment offset

  const float* biasp = L1 ? bias1 : bias0;
  float bv4[4];
  #pragma unroll
  for (int g = 0; g < 4; ++g) bv4[g] = biasp[g * 512 + j];

  f32x4 creg;
  {
    const float* ci = L1 ? c1i : c0i;
    #pragma unroll
    for (int r = 0; r < 4; ++r) creg[r] = ci[(br + r) * H_DIM + j];
  }

  if (!L1) {
    // ---------------- layer 0 ----------------
    for (int s = 0; s < T; ++s) {
      // x fragment loads (plain, streaming) — issued first
      const u16* xrow = X + ((size_t)(s * B_SZ) + mt * 16 + cc) * E_DIM + quad * 8;
      s8v xa[8];
      #pragma unroll
      for (int ks = 0; ks < 8; ++ks) xa[ks] = *(const s8v*)(xrow + ks * 32);

      // h volley in flight while x-MFMAs run
      u64 q[16][4];
      const u32* hb = H0x + (size_t)(s - 1) * (B_SZ * H_DIM) + arow;
      if (s > 0) volley16(hb, q);

      f32x4 acc[4] = {};
      #pragma unroll
      for (int ks = 0; ks < 8; ++ks) {
        int kc = ks * 4 + quad;
        #pragma unroll
        for (int g = 0; g < 4; ++g) {
          int col = g * 16 + cc;
          s8v bx = *(const s8v*)(&BsX[col * 256 + ((kc + col) & 31) * 8]);
          acc[g] = __builtin_amdgcn_mfma_f32_16x16x32_bf16(xa[ks], bx, acc[g], 0, 0, 0);
        }
      }

      PK a[16];
      if (s > 0) {
        unsigned bm = packchk16((u32)s, q, a);
        fixup16(hb, (u32)s, bm, a);
      } else {
        #pragma unroll
        for (int ks = 0; ks < 16; ++ks) a[ks].v = *(const s8v*)(h0i + arow + ks * 32);
      }
      #pragma unroll
      for (int ks = 0; ks < 16; ++ks) {
        int kc = ks * 4 + quad;
        #pragma unroll
        for (int g = 0; g < 4; ++g) {
          int col = g * 16 + cc;
          s8v bh = *(const s8v*)(&BsH[col * 512 + ((kc + col) & 63) * 8]);
          acc[g] = __builtin_amdgcn_mfma_f32_16x16x32_bf16(a[ks].v, bh, acc[g], 0, 0, 0);
        }
      }

      u32* hw = H0x + (size_t)s * (B_SZ * H_DIM);
      const u32 tg = (u32)(s + 1);
      #pragma unroll
      for (int r = 0; r < 4; ++r) {
        float gi = acc[0][r] + bv4[0];
        float gf = acc[1][r] + bv4[1];
        float gg = acc[2][r] + bv4[2];
        float go = acc[3][r] + bv4[3];
        float cn = sigf(gf) * creg[r] + sigf(gi) * tanh_(gg);
        float hn = sigf(go) * tanh_(cn);
        creg[r] = cn;
        u16 hb2 = f2bf(hn);
        __hip_atomic_store(&hw[(br + r) * H_DIM + j], ((u32)hb2 << 16) | tg,
                           __ATOMIC_RELAXED, __HIP_MEMORY_SCOPE_AGENT);
        if (s == T - 1 && h0f) {
          h0f[(br + r) * H_DIM + j] = hb2;
          c0f[(br + r) * H_DIM + j] = cn;
        }
      }
    }
  } else {
    // ---------------- layer 1 (one tick behind) ----------------
    for (int s = 0; s < T; ++s) {
      u64 q[16][4];
      PK a[16];

      // h0(s): produced one tick ago in steady state — volley + pack + fixup
      const u32* hb0 = H0x + (size_t)s * (B_SZ * H_DIM) + arow;
      volley16(hb0, q);
      {
        unsigned bm = packchk16((u32)(s + 1), q, a);
        fixup16(hb0, (u32)(s + 1), bm, a);
      }

      // issue h1(s-1) volley now (q is free): its RT hides under the x-MFMAs
      const u32* hb1 = H1x + (size_t)(s - 1) * (B_SZ * H_DIM) + arow;
      if (s > 0) volley16(hb1, q);

      f32x4 acc[4] = {};
      #pragma unroll
      for (int ks = 0; ks < 16; ++ks) {
        int kc = ks * 4 + quad;
        #pragma unroll
        for (int g = 0; g < 4; ++g) {
          int col = g * 16 + cc;
          s8v bx = *(const s8v*)(&BsX[col * 512 + ((kc + col) & 63) * 8]);
          acc[g] = __builtin_amdgcn_mfma_f32_16x16x32_bf16(a[ks].v, bx, acc[g], 0, 0, 0);
        }
      }

      if (s > 0) {
        unsigned bm = packchk16((u32)s, q, a);
        fixup16(hb1, (u32)s, bm, a);
      } else {
        #pragma unroll
        for (int ks = 0; ks < 16; ++ks) a[ks].v = *(const s8v*)(h1i + arow + ks * 32);
      }
      #pragma unroll
      for (int ks = 0; ks < 16; ++ks) {
        int kc = ks * 4 + quad;
        #pragma unroll
        for (int g = 0; g < 4; ++g) {
          int col = g * 16 + cc;
          s8v bh = *(const s8v*)(&BsH[col * 512 + ((kc + col) & 63) * 8]);
          acc[g] = __builtin_amdgcn_mfma_f32_16x16x32_bf16(a[ks].v, bh, acc[g], 0, 0, 0);
        }
      }

      u32* hw = H1x + (size_t)s * (B_SZ * H_DIM);
      const u32 tg = (u32)(s + 1);
      #pragma unroll
      for (int r = 0; r < 4; ++r) {
        float gi = acc[0][r] + bv4[0];
        float gf = acc[1][r] + bv4[1];
        float gg = acc[2][r] + bv4[2];
        float go = acc[3][r] + bv4[3];
        float cn = sigf(gf) * creg[r] + sigf(gi) * tanh_(gg);
        float hn = sigf(go) * tanh_(cn);
        creg[r] = cn;
        u16 hb2 = f2bf(hn);
        __hip_atomic_store(&hw[(br + r) * H_DIM + j], ((u32)hb2 << 16) | tg,
                           __ATOMIC_RELAXED, __HIP_MEMORY_SCOPE_AGENT);
        if (Hplain)
          Hplain[(size_t)(s * B_SZ + br + r) * H_DIM + j] = hb2;
        if (s == T - 1 && h1f) {
          h1f[(br + r) * H_DIM + j] = hb2;
          c1f[(br + r) * H_DIM + j] = cn;
        }
      }
    }
  }
}

// ---------------- zero out[:, 0, :] ----------------
__global__ void zero_t0_kernel(float* __restrict__ out) {
  int i = blockIdx.x * 256 + threadIdx.x;
  if (i >= B_SZ * V_TRG) return;
  int b = i / V_TRG, v = i - b * V_TRG;
  out[(size_t)b * (TT * V_TRG) + v] = 0.f;
}

extern "C" void kernel_launch(void* const* d_in, const int* in_sizes, int n_in,
                              void* d_out, int out_size, void* d_ws, size_t ws_size,
                              hipStream_t stream) {
  const int*   src     = (const int*)d_in[0];
  const int*   trg     = (const int*)d_in[1];
  const float* enc_emb = (const float*)d_in[2];
  const float* dec_emb = (const float*)d_in[3];
  const float* eW0i = (const float*)d_in[4];
  const float* eW0h = (const float*)d_in[5];
  const float* eb0  = (const float*)d_in[6];
  const float* eW1i = (const float*)d_in[7];
  const float* eW1h = (const float*)d_in[8];
  const float* eb1  = (const float*)d_in[9];
  const float* dW0i = (const float*)d_in[10];
  const float* dW0h = (const float*)d_in[11];
  const float* db0  = (const float*)d_in[12];
  const float* dW1i = (const float*)d_in[13];
  const float* dW1h = (const float*)d_in[14];
  const float* db1  = (const float*)d_in[15];
  const float* fcW  = (const float*)d_in[16];
  const float* fcb  = (const float*)d_in[17];
  float* out = (float*)d_out;

  char* ws = (char*)d_ws;
  size_t off = 0;
  auto alloc = [&](size_t bytes) {
    char* p = ws + off;
    off = (off + bytes + 255) & ~(size_t)255;
    return p;
  };
  u16*   hzero  = (u16*)alloc(B_SZ * H_DIM * 2);
  float* czero  = (float*)alloc(B_SZ * H_DIM * 4);
  u16* eW0i_b = (u16*)alloc((size_t)G4 * E_DIM * 2);
  u16* eW0h_b = (u16*)alloc((size_t)G4 * H_DIM * 2);
  u16* eW1i_b = (u16*)alloc((size_t)G4 * H_DIM * 2);
  u16* eW1h_b = (u16*)alloc((size_t)G4 * H_DIM * 2);
  u16* dW0i_b = (u16*)alloc((size_t)G4 * E_DIM * 2);
  u16* dW0h_b = (u16*)alloc((size_t)G4 * H_DIM * 2);
  u16* dW1i_b = (u16*)alloc((size_t)G4 * H_DIM * 2);
  u16* dW1h_b = (u16*)alloc((size_t)G4 * H_DIM * 2);
  u16* fcW_b  = (u16*)alloc((size_t)V_TRG * H_DIM * 2);
  u16* x_enc  = (u16*)alloc((size_t)TS * B_SZ * E_DIM * 2);
  u16* x_dec  = (u16*)alloc((size_t)TD * B_SZ * E_DIM * 2);
  const size_t PLANE_E = (size_t)TS * B_SZ * H_DIM;
  const size_t PLANE_D = (size_t)TD * B_SZ * H_DIM;
  u32* tagbase = (u32*)alloc((2 * PLANE_E + 2 * PLANE_D) * 4);
  u32* H0e = tagbase;
  u32* H1e = H0e + PLANE_E;
  u32* H0d = H1e + PLANE_E;
  u32* H1d = H0d + PLANE_D;
  u16* H1d_p  = (u16*)alloc((size_t)TD * B_SZ * H_DIM * 2);  // plain bf16 FC input
  u16* hF0    = (u16*)alloc(B_SZ * H_DIM * 2);
  float* cF0  = (float*)alloc(B_SZ * H_DIM * 4);
  u16* hF1    = (u16*)alloc(B_SZ * H_DIM * 2);
  float* cF1  = (float*)alloc(B_SZ * H_DIM * 4);

  hipMemsetAsync(hzero, 0, B_SZ * H_DIM * 2, stream);
  hipMemsetAsync(czero, 0, B_SZ * H_DIM * 4, stream);
  hipMemsetAsync(tagbase, 0, (2 * PLANE_E + 2 * PLANE_D) * 4, stream);

  Cvt9 c9 = {{ {eW0i, eW0i_b, G4 * E_DIM}, {eW0h, eW0h_b, G4 * H_DIM},
               {eW1i, eW1i_b, G4 * H_DIM}, {eW1h, eW1h_b, G4 * H_DIM},
               {dW0i, dW0i_b, G4 * E_DIM}, {dW0h, dW0h_b, G4 * H_DIM},
               {dW1i, dW1i_b, G4 * H_DIM}, {dW1h, dW1h_b, G4 * H_DIM},
               {fcW,  fcW_b,  V_TRG * H_DIM} }};
  cvt_kernel<<<dim3(1024, 9), 256, 0, stream>>>(c9);

  embed_kernel<<<(TS * B_SZ * E_DIM + 255) / 256, 256, 0, stream>>>(src, enc_emb, x_enc, TS * B_SZ, TS);
  embed_kernel<<<(TD * B_SZ * E_DIM + 255) / 256, 256, 0, stream>>>(trg, dec_emb, x_dec, TD * B_SZ, TT);

  // encoder: fused 2-layer pipelined scan (x-gates computed in-kernel)
  lstm2_scan<<<2 * NWG_L, 128, 0, stream>>>(
      x_enc, eW0i_b, eW0h_b, eb0, eW1i_b, eW1h_b, eb1,
      hzero, czero, hzero, czero,
      H0e, H1e, (u16*)nullptr,
      hF0, cF0, hF1, cF1, TS);

  // decoder: init = encoder final states; layer-1 h also stored plain for FC
  lstm2_scan<<<2 * NWG_L, 128, 0, stream>>>(
      x_dec, dW0i_b, dW0h_b, db0, dW1i_b, dW1h_b, db1,
      hF0, cF0, hF1, cF1,
      H0d, H1d, H1d_p,
      (u16*)nullptr, (float*)nullptr, (u16*)nullptr, (float*)nullptr, TD);

  // FC head: logits -> out[b][t+1][v]
  gemm_bf16<1><<<dim3((V_TRG + 127) / 128, (TD * B_SZ + 127) / 128), 256, 0, stream>>>(
      H1d_p, fcW_b, fcb, out, TD * B_SZ, V_TRG, H_DIM);
  zero_t0_kernel<<<(B_SZ * V_TRG + 255) / 256, 256, 0, stream>>>(out);
}